// Round 2
// baseline (5151.697 us; speedup 1.0000x reference)
//
#include <hip/hip_runtime.h>
#include <math.h>

#define B_   4
#define S_   2048
#define EIN  256
#define AD   128
#define NH   4
#define HD   32
#define TK   32
#define MTOT (B_ * S_)          /* 8192 rows */
#define SEG  1048576            /* 8192*128 */

#define OFF_PROJ 0
#define OFF_Q    (1 * SEG)
#define OFF_K    (2 * SEG)
#define OFF_V    (3 * SEG)
#define OFF_ATT  (4 * SEG)
#define OFF_T    (5 * SEG)
#define OFF_SB   (6 * SEG)
#define OFF_CAT  (7 * SEG)      /* 2*SEG floats */

__device__ float g_ws[9 * SEG];

// Y[M x 128] = X[M x KD] @ W[128 x KD]^T + b   (M = 8192, N = 128)
template <int KD>
__global__ __launch_bounds__(256)
void lin_kernel(const float* __restrict__ Xext, int xoff,
                const float* __restrict__ W, const float* __restrict__ Bv,
                int yoff)
{
    const float* X = Xext ? Xext : (const float*)(g_ws + xoff);
    float* Y = g_ws + yoff;
    __shared__ float Xs[64][33];
    __shared__ float Ws[64][33];
    const int bm = blockIdx.x * 64;
    const int bn = blockIdx.y * 64;
    const int t  = threadIdx.x;
    const int tx = t & 15, ty = t >> 4;
    float acc[4][4] = {};
    for (int kk = 0; kk < KD; kk += 32) {
        #pragma unroll
        for (int i = 0; i < 8; ++i) {
            int idx = t + i * 256;
            int r = idx >> 5, c = idx & 31;
            Xs[r][c] = X[(size_t)(bm + r) * KD + kk + c];
            Ws[r][c] = W[(size_t)(bn + r) * KD + kk + c];
        }
        __syncthreads();
        #pragma unroll
        for (int kc = 0; kc < 32; ++kc) {
            float a[4], bb[4];
            #pragma unroll
            for (int i = 0; i < 4; ++i) a[i] = Xs[ty * 4 + i][kc];
            #pragma unroll
            for (int j = 0; j < 4; ++j) bb[j] = Ws[tx * 4 + j][kc];
            #pragma unroll
            for (int i = 0; i < 4; ++i)
                #pragma unroll
                for (int j = 0; j < 4; ++j)
                    acc[i][j] = fmaf(a[i], bb[j], acc[i][j]);
        }
        __syncthreads();
    }
    #pragma unroll
    for (int i = 0; i < 4; ++i) {
        int row = bm + ty * 4 + i;
        #pragma unroll
        for (int j = 0; j < 4; ++j) {
            int col = bn + tx * 4 + j;
            Y[(size_t)row * AD + col] = acc[i][j] + Bv[col];
        }
    }
}

// One wave per q-row; exact top-32 of 2048 scores via 4-pass radix-select
// on order-preserving uint32 keys. Histogram in wave-private LDS with 8
// replicated bin copies (caps same-address atomic conflict at 8-way).
// Ties at the exact 32nd value are taken in arbitrary (not index) order —
// only matters for bit-equal boundary scores (prob ~0, continuous data).
__global__ __launch_bounds__(256, 4)
void attn_kernel(int qoff, int koff, int voff, int ooff)
{
    const float* Q = g_ws + qoff;
    const float* K = g_ws + koff;
    const float* V = g_ws + voff;
    float* O = g_ws + ooff;

    __shared__ __align__(16) unsigned bins[4][8][256];
    __shared__ unsigned cnts[4][2];
    __shared__ float svv[4][32];
    __shared__ int  sjj[4][32];

    const int bh   = blockIdx.x;          // 0..15
    const int b    = bh >> 2, h = bh & 3;
    const int wid  = threadIdx.x >> 6;    // 4 waves/block
    const int lane = threadIdx.x & 63;
    unsigned (*mybins)[256] = bins[wid];
    unsigned* mycnt = cnts[wid];
    float* mysv = svv[wid];
    int*   mysj = sjj[wid];
    const int myrep = lane & 7;

    const size_t rowbase = (size_t)b * S_;
    const float* kbase = K + rowbase * AD + h * HD;
    const float* vbase = V + rowbase * AD + h * HD;
    const float scale = 0.17677669529663688f;  // 1/sqrt(32): monotone

    for (int r = 0; r < 4; ++r) {
        const int qrow = blockIdx.y * 16 + wid * 4 + r;
        const float4* qp4 = (const float4*)(Q + (rowbase + qrow) * AD + h * HD);
        float4 qv[8];
        #pragma unroll
        for (int i = 0; i < 8; ++i) qv[i] = qp4[i];

        // ---- score phase: lane owns k-indices {lane + 64*t} ----
        unsigned keys[32];
        #pragma unroll
        for (int t = 0; t < 32; ++t) {
            const float4* kp4 = (const float4*)(kbase + (size_t)(t * 64 + lane) * AD);
            float s = 0.f;
            #pragma unroll
            for (int i = 0; i < 8; ++i) {
                float4 kv = kp4[i];
                s = fmaf(qv[i].x, kv.x, s); s = fmaf(qv[i].y, kv.y, s);
                s = fmaf(qv[i].z, kv.z, s); s = fmaf(qv[i].w, kv.w, s);
            }
            s *= scale;
            unsigned u = __float_as_uint(s);
            keys[t] = (u & 0x80000000u) ? ~u : (u | 0x80000000u);
        }

        // ---- radix-select: T = 32nd-largest key, rank = #eq-to-take ----
        unsigned alive = 0xFFFFFFFFu, prefixT = 0u;
        int rank = TK;
        #pragma unroll
        for (int pass = 0; pass < 4; ++pass) {
            const int shift = 24 - 8 * pass;
            uint4 z; z.x = z.y = z.z = z.w = 0u;
            #pragma unroll
            for (int rp = 0; rp < 8; ++rp) ((uint4*)mybins[rp])[lane] = z;
            asm volatile("s_waitcnt lgkmcnt(0)" ::: "memory");
            #pragma unroll
            for (int t = 0; t < 32; ++t) {
                if ((alive >> t) & 1u) {
                    unsigned d = (keys[t] >> shift) & 0xFFu;
                    atomicAdd(&mybins[myrep][d], 1u);
                }
            }
            asm volatile("s_waitcnt lgkmcnt(0)" ::: "memory");
            // lane holds digits 4*lane .. 4*lane+3 (h0..h3), merged replicas
            unsigned h0 = 0, h1 = 0, h2 = 0, h3 = 0;
            #pragma unroll
            for (int rp = 0; rp < 8; ++rp) {
                uint4 x = ((uint4*)mybins[rp])[lane];
                h0 += x.x; h1 += x.y; h2 += x.z; h3 += x.w;
            }
            unsigned tsum = h0 + h1 + h2 + h3;
            // wave suffix-inclusive scan of tsum (sum over lanes >= me)
            unsigned inc = tsum;
            #pragma unroll
            for (int off = 1; off < 64; off <<= 1) {
                int sl = lane + off;
                unsigned o = (unsigned)__shfl((int)inc, sl);
                inc += (sl < 64) ? o : 0u;
            }
            unsigned excl = inc - tsum;           // digits in higher lanes
            unsigned a3 = excl, a2 = a3 + h3, a1 = a2 + h2, a0 = a1 + h1;
            int dl = -1; unsigned ab = 0;
            unsigned rk = (unsigned)rank;
            if (a0 < rk && rk <= a0 + h0) { dl = 4 * lane + 0; ab = a0; }
            if (a1 < rk && rk <= a1 + h1) { dl = 4 * lane + 1; ab = a1; }
            if (a2 < rk && rk <= a2 + h2) { dl = 4 * lane + 2; ab = a2; }
            if (a3 < rk && rk <= a3 + h3) { dl = 4 * lane + 3; ab = a3; }
            unsigned long long fm = __ballot(dl >= 0);
            int src = (int)__builtin_ctzll(fm);
            int dstar = __shfl(dl, src);
            rank = rank - __shfl((int)ab, src);
            prefixT |= ((unsigned)dstar) << shift;
            unsigned nal = 0u;
            #pragma unroll
            for (int t = 0; t < 32; ++t) {
                if (((alive >> t) & 1u) &&
                    (((keys[t] >> shift) & 0xFFu) == (unsigned)dstar))
                    nal |= (1u << t);
            }
            alive = nal;
        }

        // ---- compaction: all keys > T, plus `rank` keys == T ----
        const int cgt = TK - rank;
        if (lane == 0) { mycnt[0] = 0u; mycnt[1] = 0u; }
        asm volatile("s_waitcnt lgkmcnt(0)" ::: "memory");
        #pragma unroll
        for (int t = 0; t < 32; ++t) {
            unsigned kk = keys[t];
            if (kk > prefixT) {
                unsigned s0 = atomicAdd(&mycnt[0], 1u);
                unsigned iu = (kk & 0x80000000u) ? (kk & 0x7FFFFFFFu) : ~kk;
                mysv[s0] = __uint_as_float(iu);
                mysj[s0] = t * 64 + lane;
            } else if (kk == prefixT) {
                unsigned e = atomicAdd(&mycnt[1], 1u);
                if ((int)e < rank) {
                    unsigned iu = (kk & 0x80000000u) ? (kk & 0x7FFFFFFFu) : ~kk;
                    mysv[cgt + e] = __uint_as_float(iu);
                    mysj[cgt + e] = t * 64 + lane;
                }
            }
        }
        asm volatile("s_waitcnt lgkmcnt(0)" ::: "memory");

        // ---- softmax over 32 selected ----
        float v = (lane < TK) ? mysv[lane] : -3.0e38f;
        int  jj = (lane < TK) ? mysj[lane] : 0;
        float m = v;
        #pragma unroll
        for (int off = 1; off < 64; off <<= 1) m = fmaxf(m, __shfl_xor(m, off));
        float e = (lane < TK) ? __expf(v - m) : 0.f;
        float ssum = e;
        #pragma unroll
        for (int off = 1; off < 64; off <<= 1) ssum += __shfl_xor(ssum, off);
        float w = e / ssum;

        // ---- out[d] = sum_i w_i * v[idx_i][d] ----
        float oacc = 0.f;
        const int dd = lane & 31, half = lane >> 5;
        #pragma unroll
        for (int u2 = 0; u2 < 16; ++u2) {
            int i = half * 16 + u2;
            float wi = __shfl(w, i);
            int  ji  = __shfl(jj, i);
            oacc = fmaf(wi, vbase[(size_t)ji * AD + dd], oacc);
        }
        oacc += __shfl_down(oacc, 32);
        if (lane < HD) O[(rowbase + qrow) * AD + h * HD + lane] = oacc;
    }
}

__global__ __launch_bounds__(256)
void concat_kernel()
{
    int i = blockIdx.x * 256 + threadIdx.x;   // over 8192*256
    int row = i >> 8, c = i & 255;
    float v = (c < AD) ? g_ws[OFF_T + row * AD + c]
                       : g_ws[OFF_SB + row * AD + (c - AD)];
    g_ws[OFF_CAT + i] = v;
}

__global__ __launch_bounds__(256)
void fuse_kernel(float* __restrict__ out)
{
    int i = blockIdx.x * 256 + threadIdx.x;   // over 8192*128
    float g = g_ws[OFF_Q + i];
    float f = g_ws[OFF_K + i];
    out[i] = f / (1.0f + expf(-g));           // f * sigmoid(g)
}

extern "C" void kernel_launch(void* const* d_in, const int* in_sizes, int n_in,
                              void* d_out, int out_size, void* d_ws, size_t ws_size,
                              hipStream_t stream)
{
    (void)in_sizes; (void)n_in; (void)d_ws; (void)ws_size; (void)out_size;
    const float* x      = (const float*)d_in[0];
    const float* tp_w   = (const float*)d_in[1];
    const float* tp_b   = (const float*)d_in[2];
    const float* sp_w   = (const float*)d_in[3];
    const float* sp_b   = (const float*)d_in[4];
    const float* gate_w = (const float*)d_in[21];
    const float* gate_b = (const float*)d_in[22];
    const float* fus_w  = (const float*)d_in[23];
    const float* fus_b  = (const float*)d_in[24];

    dim3 gl(128, 2);
    for (int br = 0; br < 2; ++br) {
        const float* pw = br ? sp_w : tp_w;
        const float* pb = br ? sp_b : tp_b;
        int base = 5 + br * 8;
        const float* qw = (const float*)d_in[base + 0];
        const float* qb = (const float*)d_in[base + 1];
        const float* kw = (const float*)d_in[base + 2];
        const float* kb = (const float*)d_in[base + 3];
        const float* vw = (const float*)d_in[base + 4];
        const float* vb = (const float*)d_in[base + 5];
        const float* ow = (const float*)d_in[base + 6];
        const float* ob = (const float*)d_in[base + 7];

        lin_kernel<256><<<gl, 256, 0, stream>>>(x, 0, pw, pb, OFF_PROJ);
        lin_kernel<128><<<gl, 256, 0, stream>>>(nullptr, OFF_PROJ, qw, qb, OFF_Q);
        lin_kernel<128><<<gl, 256, 0, stream>>>(nullptr, OFF_PROJ, kw, kb, OFF_K);
        lin_kernel<128><<<gl, 256, 0, stream>>>(nullptr, OFF_PROJ, vw, vb, OFF_V);
        attn_kernel<<<dim3(16, 128), 256, 0, stream>>>(OFF_Q, OFF_K, OFF_V, OFF_ATT);
        lin_kernel<128><<<gl, 256, 0, stream>>>(nullptr, OFF_ATT, ow, ob,
                                                br ? OFF_SB : OFF_T);
    }
    concat_kernel<<<8192, 256, 0, stream>>>();
    lin_kernel<256><<<gl, 256, 0, stream>>>(nullptr, OFF_CAT, gate_w, gate_b, OFF_Q);
    lin_kernel<256><<<gl, 256, 0, stream>>>(nullptr, OFF_CAT, fus_w, fus_b, OFF_K);
    fuse_kernel<<<4096, 256, 0, stream>>>((float*)d_out);
}

// Round 3
// 3602.254 us; speedup vs baseline: 1.4301x; 1.4301x over previous
//
#include <hip/hip_runtime.h>
#include <math.h>

#define B_   4
#define S_   2048
#define EIN  256
#define AD   128
#define NH   4
#define HD   32
#define TK   32
#define MTOT (B_ * S_)          /* 8192 rows */
#define SEG  1048576            /* 8192*128 */
#define CAP  192                /* survivor capacity per wave */

#define OFF_PROJ 0
#define OFF_Q    (1 * SEG)
#define OFF_K    (2 * SEG)
#define OFF_V    (3 * SEG)
#define OFF_ATT  (4 * SEG)
#define OFF_T    (5 * SEG)
#define OFF_SB   (6 * SEG)
#define OFF_CAT  (7 * SEG)      /* 2*SEG floats */

__device__ float g_ws[9 * SEG];

__device__ __forceinline__ unsigned f2key(float s) {
    unsigned u = __float_as_uint(s);
    return (u & 0x80000000u) ? ~u : (u | 0x80000000u);
}
__device__ __forceinline__ float key2f(unsigned k) {
    unsigned u = (k & 0x80000000u) ? (k & 0x7FFFFFFFu) : ~k;
    return __uint_as_float(u);
}

// Y[M x 128] = X[M x KD] @ W[128 x KD]^T + b   (M = 8192, N = 128)
template <int KD>
__global__ __launch_bounds__(256)
void lin_kernel(const float* __restrict__ Xext, int xoff,
                const float* __restrict__ W, const float* __restrict__ Bv,
                int yoff)
{
    const float* X = Xext ? Xext : (const float*)(g_ws + xoff);
    float* Y = g_ws + yoff;
    __shared__ float Xs[64][33];
    __shared__ float Ws[64][33];
    const int bm = blockIdx.x * 64;
    const int bn = blockIdx.y * 64;
    const int t  = threadIdx.x;
    const int tx = t & 15, ty = t >> 4;
    float acc[4][4] = {};
    for (int kk = 0; kk < KD; kk += 32) {
        #pragma unroll
        for (int i = 0; i < 8; ++i) {
            int idx = t + i * 256;
            int r = idx >> 5, c = idx & 31;
            Xs[r][c] = X[(size_t)(bm + r) * KD + kk + c];
            Ws[r][c] = W[(size_t)(bn + r) * KD + kk + c];
        }
        __syncthreads();
        #pragma unroll
        for (int kc = 0; kc < 32; ++kc) {
            float a[4], bb[4];
            #pragma unroll
            for (int i = 0; i < 4; ++i) a[i] = Xs[ty * 4 + i][kc];
            #pragma unroll
            for (int j = 0; j < 4; ++j) bb[j] = Ws[tx * 4 + j][kc];
            #pragma unroll
            for (int i = 0; i < 4; ++i)
                #pragma unroll
                for (int j = 0; j < 4; ++j)
                    acc[i][j] = fmaf(a[i], bb[j], acc[i][j]);
        }
        __syncthreads();
    }
    #pragma unroll
    for (int i = 0; i < 4; ++i) {
        int row = bm + ty * 4 + i;
        #pragma unroll
        for (int j = 0; j < 4; ++j) {
            int col = bn + tx * 4 + j;
            Y[(size_t)row * AD + col] = acc[i][j] + Bv[col];
        }
    }
}

// One wave per q-row. Exact top-32 via threshold-prefilter + rank-by-count:
//  thr = 32nd-largest of the 64 per-lane maxima (bitonic sort across lanes)
//  => provably <= true 32nd value => survivors (~44 expected) superset of top-32.
//  Survivors packed (key<<32)|(2047-idx): u64 order == (value desc, index asc)
//  == lax.top_k order. rank<32 => selected, rank == output slot (no atomics).
__global__ __launch_bounds__(256)
void attn_kernel(int qoff, int koff, int voff, int ooff)
{
    const float* Q = g_ws + qoff;
    const float* K = g_ws + koff;
    const float* V = g_ws + voff;
    float* O = g_ws + ooff;

    __shared__ unsigned long long sve[4][CAP];
    __shared__ float    wsel[4][32];
    __shared__ unsigned jsel[4][32];

    const int bh   = blockIdx.x;          // 0..15
    const int b    = bh >> 2, h = bh & 3;
    const int wid  = threadIdx.x >> 6;    // 4 waves/block
    const int lane = threadIdx.x & 63;
    unsigned long long* sv = sve[wid];
    float*    wp = wsel[wid];
    unsigned* jp = jsel[wid];

    const size_t rowbase = (size_t)b * S_;
    const float* kbase = K + rowbase * AD + h * HD;
    const float* vbase = V + rowbase * AD + h * HD;
    const float scale = 0.17677669529663688f;  // 1/sqrt(32): monotone

    for (int r = 0; r < 4; ++r) {
        const int qrow = blockIdx.y * 16 + wid * 4 + r;
        const float4* qp4 = (const float4*)(Q + (rowbase + qrow) * AD + h * HD);
        float4 qv[8];
        #pragma unroll
        for (int i = 0; i < 8; ++i) qv[i] = qp4[i];

        // ---- scores: lane owns k-indices {lane + 64*t} ----
        unsigned keys[32];
        unsigned lmax = 0u;
        #pragma unroll
        for (int t = 0; t < 32; ++t) {
            const float4* kp4 = (const float4*)(kbase + (size_t)(t * 64 + lane) * AD);
            float s = 0.f;
            #pragma unroll
            for (int i = 0; i < 8; ++i) {
                float4 kv = kp4[i];
                s = fmaf(qv[i].x, kv.x, s); s = fmaf(qv[i].y, kv.y, s);
                s = fmaf(qv[i].z, kv.z, s); s = fmaf(qv[i].w, kv.w, s);
            }
            unsigned kk = f2key(s * scale);
            keys[t] = kk;
            lmax = (kk > lmax) ? kk : lmax;
        }

        // ---- bitonic sort (ascending) of 64 lane maxima ----
        unsigned bs = lmax;
        #pragma unroll
        for (int k = 2; k <= 64; k <<= 1) {
            #pragma unroll
            for (int j = k >> 1; j > 0; j >>= 1) {
                unsigned o = (unsigned)__shfl_xor((int)bs, j);
                bool up = ((lane & k) == 0);
                bool lower = ((lane & j) == 0);
                bs = (up == lower) ? (bs < o ? bs : o) : (bs > o ? bs : o);
            }
        }
        const unsigned thr  = (unsigned)__shfl((int)bs, 32); // 32nd-largest lane max
        const unsigned mkey = (unsigned)__shfl((int)bs, 63); // global max
        const float Mf = key2f(mkey);

        // fence: prior iteration's LDS reads done before overwriting sve
        asm volatile("s_waitcnt lgkmcnt(0)" ::: "memory");

        // ---- ballot-compact survivors (keys >= thr) ----
        int base = 0;
        const unsigned long long lt = (1ull << lane) - 1ull;
        #pragma unroll
        for (int t = 0; t < 32; ++t) {
            bool pred = keys[t] >= thr;
            unsigned long long m = __ballot(pred);
            int slot = base + __popcll(m & lt);
            if (pred && slot < CAP)
                sv[slot] = ((unsigned long long)keys[t] << 32)
                         | (unsigned)(2047 - (t * 64 + lane));
            base += __popcll(m);
        }
        const int S = base;
        asm volatile("s_waitcnt lgkmcnt(0)" ::: "memory");

        if (S <= 64) {
            // ---- rank by counting: lane i owns survivor i ----
            unsigned long long pi = (lane < S) ? sv[lane] : 0ull;
            int rank = 0;
            for (int jx = 0; jx < S; ++jx) {
                unsigned long long pj = sv[jx];
                rank += (pj > pi) ? 1 : 0;
            }
            float e = 0.f;
            unsigned ji = 0;
            if (lane < S && rank < TK) {
                float val = key2f((unsigned)(pi >> 32));
                e = __expf(val - Mf);
                ji = 2047u - (unsigned)(pi & 0xFFFFFFFFull);
            }
            float esum = e;
            #pragma unroll
            for (int off = 1; off < 64; off <<= 1) esum += __shfl_xor(esum, off);
            if (lane < S && rank < TK) { wp[rank] = e / esum; jp[rank] = ji; }
        } else if (S <= CAP) {
            unsigned long long pi[3]; int rk[3]; float ee[3]; unsigned jj[3];
            float esum = 0.f;
            #pragma unroll
            for (int u = 0; u < 3; ++u) {
                int i = lane + u * 64;
                pi[u] = (i < S) ? sv[i] : 0ull;
                rk[u] = 9999; ee[u] = 0.f; jj[u] = 0;
            }
            for (int jx = 0; jx < S; ++jx) {
                unsigned long long pj = sv[jx];
                #pragma unroll
                for (int u = 0; u < 3; ++u)
                    rk[u] += (pj > pi[u]) ? 1 : 0;
            }
            #pragma unroll
            for (int u = 0; u < 3; ++u) {
                int i = lane + u * 64;
                if (i < S) rk[u] -= 9999;
                if (i < S && rk[u] < TK) {
                    float val = key2f((unsigned)(pi[u] >> 32));
                    ee[u] = __expf(val - Mf);
                    jj[u] = 2047u - (unsigned)(pi[u] & 0xFFFFFFFFull);
                    esum += ee[u];
                }
            }
            #pragma unroll
            for (int off = 1; off < 64; off <<= 1) esum += __shfl_xor(esum, off);
            #pragma unroll
            for (int u = 0; u < 3; ++u) {
                int i = lane + u * 64;
                if (i < S && rk[u] < TK) { wp[rk[u]] = ee[u] / esum; jp[rk[u]] = jj[u]; }
            }
        } else {
            // ---- exact fallback: iterative argmax (value desc, idx asc) ----
            unsigned consumed = 0u;
            for (int i = 0; i < TK; ++i) {
                unsigned bk = 0u; unsigned gj = 0xFFFFFFFFu;
                #pragma unroll
                for (int t = 0; t < 32; ++t) {
                    if (((consumed >> t) & 1u) == 0u) {
                        unsigned kk = keys[t]; unsigned j = (unsigned)(t * 64 + lane);
                        if (kk > bk || (kk == bk && j < gj)) { bk = kk; gj = j; }
                    }
                }
                #pragma unroll
                for (int off = 1; off < 64; off <<= 1) {
                    unsigned ok = (unsigned)__shfl_xor((int)bk, off);
                    unsigned oj = (unsigned)__shfl_xor((int)gj, off);
                    if (ok > bk || (ok == bk && oj < gj)) { bk = ok; gj = oj; }
                }
                if ((gj & 63u) == (unsigned)lane) consumed |= (1u << (gj >> 6));
                if (lane == 0) { wp[i] = key2f(bk); jp[i] = gj; }
            }
            asm volatile("s_waitcnt lgkmcnt(0)" ::: "memory");
            float v = (lane < TK) ? wp[lane] : 0.f;
            float e = (lane < TK) ? __expf(v - Mf) : 0.f;
            float esum = e;
            #pragma unroll
            for (int off = 1; off < 64; off <<= 1) esum += __shfl_xor(esum, off);
            if (lane < TK) wp[lane] = e / esum;
        }
        asm volatile("s_waitcnt lgkmcnt(0)" ::: "memory");

        // ---- out[dd] = sum_i w_i * v[idx_i][dd] ----
        float oacc = 0.f;
        const int dd = lane & 31, half = lane >> 5;
        #pragma unroll
        for (int u2 = 0; u2 < 16; ++u2) {
            int i = half * 16 + u2;
            float wi = wp[i];
            unsigned ji = jp[i];
            oacc = fmaf(wi, vbase[(size_t)ji * AD + dd], oacc);
        }
        oacc += __shfl_down(oacc, 32);
        if (lane < HD) O[(rowbase + qrow) * AD + h * HD + lane] = oacc;
    }
}

__global__ __launch_bounds__(256)
void concat_kernel()
{
    int i = blockIdx.x * 256 + threadIdx.x;   // over 8192*256
    int row = i >> 8, c = i & 255;
    float v = (c < AD) ? g_ws[OFF_T + row * AD + c]
                       : g_ws[OFF_SB + row * AD + (c - AD)];
    g_ws[OFF_CAT + i] = v;
}

__global__ __launch_bounds__(256)
void fuse_kernel(float* __restrict__ out)
{
    int i = blockIdx.x * 256 + threadIdx.x;   // over 8192*128
    float g = g_ws[OFF_Q + i];
    float f = g_ws[OFF_K + i];
    out[i] = f / (1.0f + expf(-g));           // f * sigmoid(g)
}

extern "C" void kernel_launch(void* const* d_in, const int* in_sizes, int n_in,
                              void* d_out, int out_size, void* d_ws, size_t ws_size,
                              hipStream_t stream)
{
    (void)in_sizes; (void)n_in; (void)d_ws; (void)ws_size; (void)out_size;
    const float* x      = (const float*)d_in[0];
    const float* tp_w   = (const float*)d_in[1];
    const float* tp_b   = (const float*)d_in[2];
    const float* sp_w   = (const float*)d_in[3];
    const float* sp_b   = (const float*)d_in[4];
    const float* gate_w = (const float*)d_in[21];
    const float* gate_b = (const float*)d_in[22];
    const float* fus_w  = (const float*)d_in[23];
    const float* fus_b  = (const float*)d_in[24];

    dim3 gl(128, 2);
    for (int br = 0; br < 2; ++br) {
        const float* pw = br ? sp_w : tp_w;
        const float* pb = br ? sp_b : tp_b;
        int base = 5 + br * 8;
        const float* qw = (const float*)d_in[base + 0];
        const float* qb = (const float*)d_in[base + 1];
        const float* kw = (const float*)d_in[base + 2];
        const float* kb = (const float*)d_in[base + 3];
        const float* vw = (const float*)d_in[base + 4];
        const float* vb = (const float*)d_in[base + 5];
        const float* ow = (const float*)d_in[base + 6];
        const float* ob = (const float*)d_in[base + 7];

        lin_kernel<256><<<gl, 256, 0, stream>>>(x, 0, pw, pb, OFF_PROJ);
        lin_kernel<128><<<gl, 256, 0, stream>>>(nullptr, OFF_PROJ, qw, qb, OFF_Q);
        lin_kernel<128><<<gl, 256, 0, stream>>>(nullptr, OFF_PROJ, kw, kb, OFF_K);
        lin_kernel<128><<<gl, 256, 0, stream>>>(nullptr, OFF_PROJ, vw, vb, OFF_V);
        attn_kernel<<<dim3(16, 128), 256, 0, stream>>>(OFF_Q, OFF_K, OFF_V, OFF_ATT);
        lin_kernel<128><<<gl, 256, 0, stream>>>(nullptr, OFF_ATT, ow, ob,
                                                br ? OFF_SB : OFF_T);
    }
    concat_kernel<<<8192, 256, 0, stream>>>();
    lin_kernel<256><<<gl, 256, 0, stream>>>(nullptr, OFF_CAT, gate_w, gate_b, OFF_Q);
    lin_kernel<256><<<gl, 256, 0, stream>>>(nullptr, OFF_CAT, fus_w, fus_b, OFF_K);
    fuse_kernel<<<4096, 256, 0, stream>>>((float*)d_out);
}

// Round 4
// 451.797 us; speedup vs baseline: 11.4027x; 7.9732x over previous
//
#include <hip/hip_runtime.h>
#include <math.h>

#define B_   4
#define S_   2048
#define AD   128
#define NH   4
#define HD   32
#define TK   32
#define SEG  1048576            /* 8192*128 */
#define CAP  192                /* survivor capacity per wave */

#define OFF_PROJ 0
#define OFF_Q    (1 * SEG)
#define OFF_K    (2 * SEG)
#define OFF_V    (3 * SEG)
#define OFF_ATT  (4 * SEG)
#define OFF_T    (5 * SEG)
#define OFF_SB   (6 * SEG)
#define OFF_CAT  (7 * SEG)      /* 2*SEG floats */

__device__ float g_ws[9 * SEG];
__device__ float g_sc[16 * S_ * S_];   /* 268 MB score scratch, reused per branch */

__device__ __forceinline__ unsigned f2key(float s) {
    unsigned u = __float_as_uint(s);
    return (u & 0x80000000u) ? ~u : (u | 0x80000000u);
}
__device__ __forceinline__ float key2f(unsigned k) {
    unsigned u = (k & 0x80000000u) ? (k & 0x7FFFFFFFu) : ~k;
    return __uint_as_float(u);
}

// Y[M x 128] = X[M x KD] @ W[128 x KD]^T + b   (M = 8192, N = 128)
template <int KD>
__global__ __launch_bounds__(256)
void lin_kernel(const float* __restrict__ Xext, int xoff,
                const float* __restrict__ W, const float* __restrict__ Bv,
                int yoff)
{
    const float* X = Xext ? Xext : (const float*)(g_ws + xoff);
    float* Y = g_ws + yoff;
    __shared__ float Xs[64][33];
    __shared__ float Ws[64][33];
    const int bm = blockIdx.x * 64;
    const int bn = blockIdx.y * 64;
    const int t  = threadIdx.x;
    const int tx = t & 15, ty = t >> 4;
    float acc[4][4] = {};
    for (int kk = 0; kk < KD; kk += 32) {
        #pragma unroll
        for (int i = 0; i < 8; ++i) {
            int idx = t + i * 256;
            int r = idx >> 5, c = idx & 31;
            Xs[r][c] = X[(size_t)(bm + r) * KD + kk + c];
            Ws[r][c] = W[(size_t)(bn + r) * KD + kk + c];
        }
        __syncthreads();
        #pragma unroll
        for (int kc = 0; kc < 32; ++kc) {
            float a[4], bb[4];
            #pragma unroll
            for (int i = 0; i < 4; ++i) a[i] = Xs[ty * 4 + i][kc];
            #pragma unroll
            for (int j = 0; j < 4; ++j) bb[j] = Ws[tx * 4 + j][kc];
            #pragma unroll
            for (int i = 0; i < 4; ++i)
                #pragma unroll
                for (int j = 0; j < 4; ++j)
                    acc[i][j] = fmaf(a[i], bb[j], acc[i][j]);
        }
        __syncthreads();
    }
    #pragma unroll
    for (int i = 0; i < 4; ++i) {
        int row = bm + ty * 4 + i;
        #pragma unroll
        for (int j = 0; j < 4; ++j) {
            int col = bn + tx * 4 + j;
            Y[(size_t)row * AD + col] = acc[i][j] + Bv[col];
        }
    }
}

// Three GEMMs sharing one X, selected by blockIdx.z (QKV / gate+fus fusion).
template <int KD>
__global__ __launch_bounds__(256)
void lin3_kernel(int xoff,
                 const float* __restrict__ W0, const float* __restrict__ B0, int y0,
                 const float* __restrict__ W1, const float* __restrict__ B1, int y1,
                 const float* __restrict__ W2, const float* __restrict__ B2, int y2)
{
    const int z = blockIdx.z;
    const float* X = (const float*)(g_ws + xoff);
    const float* W = (z == 0) ? W0 : (z == 1) ? W1 : W2;
    const float* Bv = (z == 0) ? B0 : (z == 1) ? B1 : B2;
    float* Y = g_ws + ((z == 0) ? y0 : (z == 1) ? y1 : y2);
    __shared__ float Xs[64][33];
    __shared__ float Ws[64][33];
    const int bm = blockIdx.x * 64;
    const int bn = blockIdx.y * 64;
    const int t  = threadIdx.x;
    const int tx = t & 15, ty = t >> 4;
    float acc[4][4] = {};
    for (int kk = 0; kk < KD; kk += 32) {
        #pragma unroll
        for (int i = 0; i < 8; ++i) {
            int idx = t + i * 256;
            int r = idx >> 5, c = idx & 31;
            Xs[r][c] = X[(size_t)(bm + r) * KD + kk + c];
            Ws[r][c] = W[(size_t)(bn + r) * KD + kk + c];
        }
        __syncthreads();
        #pragma unroll
        for (int kc = 0; kc < 32; ++kc) {
            float a[4], bb[4];
            #pragma unroll
            for (int i = 0; i < 4; ++i) a[i] = Xs[ty * 4 + i][kc];
            #pragma unroll
            for (int j = 0; j < 4; ++j) bb[j] = Ws[tx * 4 + j][kc];
            #pragma unroll
            for (int i = 0; i < 4; ++i)
                #pragma unroll
                for (int j = 0; j < 4; ++j)
                    acc[i][j] = fmaf(a[i], bb[j], acc[i][j]);
        }
        __syncthreads();
    }
    #pragma unroll
    for (int i = 0; i < 4; ++i) {
        int row = bm + ty * 4 + i;
        #pragma unroll
        for (int j = 0; j < 4; ++j) {
            int col = bn + tx * 4 + j;
            Y[(size_t)row * AD + col] = acc[i][j] + Bv[col];
        }
    }
}

// scores[bh][q][k] = scale * sum_d Q[q][d] K[k][d]  (per-head 2048x2048x32 GEMM)
__global__ __launch_bounds__(256)
void score_kernel(int qoff, int koff)
{
    const int bh = blockIdx.z, b = bh >> 2, h = bh & 3;
    const float* Q = g_ws + qoff + (size_t)b * S_ * AD + h * HD;
    const float* K = g_ws + koff + (size_t)b * S_ * AD + h * HD;
    float* Sc = g_sc + (size_t)bh * S_ * S_;
    __shared__ float Qs[64][33];
    __shared__ float Ks[64][33];
    const int t = threadIdx.x, tx = t & 15, ty = t >> 4;
    const int q0 = blockIdx.y * 64, k0 = blockIdx.x * 64;
    #pragma unroll
    for (int i = 0; i < 8; ++i) {
        int idx = t + i * 256;
        int r = idx >> 5, c = idx & 31;
        Qs[r][c] = Q[(size_t)(q0 + r) * AD + c];
        Ks[r][c] = K[(size_t)(k0 + r) * AD + c];
    }
    __syncthreads();
    float acc[4][4] = {};
    #pragma unroll
    for (int kc = 0; kc < 32; ++kc) {
        float a[4], bb[4];
        #pragma unroll
        for (int i = 0; i < 4; ++i) a[i] = Qs[ty * 4 + i][kc];
        #pragma unroll
        for (int j = 0; j < 4; ++j) bb[j] = Ks[tx * 4 + j][kc];
        #pragma unroll
        for (int i = 0; i < 4; ++i)
            #pragma unroll
            for (int j = 0; j < 4; ++j)
                acc[i][j] = fmaf(a[i], bb[j], acc[i][j]);
    }
    const float scale = 0.17677669529663688f;  // 1/sqrt(32)
    #pragma unroll
    for (int i = 0; i < 4; ++i) {
        float4 o;
        o.x = acc[i][0] * scale; o.y = acc[i][1] * scale;
        o.z = acc[i][2] * scale; o.w = acc[i][3] * scale;
        *(float4*)(Sc + (size_t)(q0 + ty * 4 + i) * S_ + k0 + tx * 4) = o;
    }
}

// One wave per q-row: coalesced score-row read, exact top-32 via
// threshold-prefilter + rank-by-count (order == lax.top_k), softmax, V-gather.
__global__ __launch_bounds__(256)
void topk_kernel(int voff, int ooff)
{
    const float* V = g_ws + voff;
    float* O = g_ws + ooff;

    __shared__ unsigned long long sve[4][CAP];
    __shared__ float    wsel[4][32];
    __shared__ unsigned jsel[4][32];

    const int wid  = threadIdx.x >> 6;
    const int lane = threadIdx.x & 63;
    const int gr   = blockIdx.x * 4 + wid;     // 0..32767
    const int bh   = gr >> 11, q = gr & 2047;
    const int b    = bh >> 2,  h = bh & 3;

    unsigned long long* sv = sve[wid];
    float*    wp = wsel[wid];
    unsigned* jp = jsel[wid];

    const float* Srow  = g_sc + (size_t)bh * S_ * S_ + (size_t)q * S_;
    const float* vbase = V + (size_t)b * S_ * AD + h * HD;

    // ---- load 32 keys/lane, coalesced float4; j(t) = (t>>2)*256 + lane*4 + (t&3)
    unsigned keys[32];
    unsigned lmax = 0u;
    #pragma unroll
    for (int i = 0; i < 8; ++i) {
        float4 s4 = ((const float4*)Srow)[i * 64 + lane];
        unsigned k0 = f2key(s4.x), k1 = f2key(s4.y);
        unsigned k2 = f2key(s4.z), k3 = f2key(s4.w);
        keys[i * 4 + 0] = k0; keys[i * 4 + 1] = k1;
        keys[i * 4 + 2] = k2; keys[i * 4 + 3] = k3;
        unsigned m01 = (k0 > k1) ? k0 : k1;
        unsigned m23 = (k2 > k3) ? k2 : k3;
        unsigned m = (m01 > m23) ? m01 : m23;
        lmax = (m > lmax) ? m : lmax;
    }

    // ---- bitonic sort (ascending) of 64 lane maxima ----
    unsigned bs = lmax;
    #pragma unroll
    for (int k = 2; k <= 64; k <<= 1) {
        #pragma unroll
        for (int j = k >> 1; j > 0; j >>= 1) {
            unsigned o = (unsigned)__shfl_xor((int)bs, j);
            bool up = ((lane & k) == 0);
            bool lower = ((lane & j) == 0);
            bs = (up == lower) ? (bs < o ? bs : o) : (bs > o ? bs : o);
        }
    }
    const unsigned thr  = (unsigned)__shfl((int)bs, 32); // 32nd-largest lane max <= T32
    const unsigned mkey = (unsigned)__shfl((int)bs, 63); // global max
    const float Mf = key2f(mkey);

    // ---- ballot-compact survivors (keys >= thr) ----
    int base = 0;
    const unsigned long long lt = (1ull << lane) - 1ull;
    #pragma unroll
    for (int t = 0; t < 32; ++t) {
        bool pred = keys[t] >= thr;
        unsigned long long m = __ballot(pred);
        int slot = base + __popcll(m & lt);
        if (pred && slot < CAP) {
            unsigned jidx = (unsigned)((t >> 2) * 256 + lane * 4 + (t & 3));
            sv[slot] = ((unsigned long long)keys[t] << 32) | (unsigned)(2047 - jidx);
        }
        base += __popcll(m);
    }
    const int S = base;
    asm volatile("s_waitcnt lgkmcnt(0)" ::: "memory");

    if (S <= 64) {
        unsigned long long pi = (lane < S) ? sv[lane] : 0ull;
        int rank = 0;
        for (int jx = 0; jx < S; ++jx)
            rank += (sv[jx] > pi) ? 1 : 0;
        float e = 0.f; unsigned ji = 0;
        if (lane < S && rank < TK) {
            float val = key2f((unsigned)(pi >> 32));
            e = __expf(val - Mf);
            ji = 2047u - (unsigned)(pi & 0xFFFFFFFFull);
        }
        float esum = e;
        #pragma unroll
        for (int off = 1; off < 64; off <<= 1) esum += __shfl_xor(esum, off);
        if (lane < S && rank < TK) { wp[rank] = e / esum; jp[rank] = ji; }
    } else if (S <= CAP) {
        unsigned long long pi[3]; int rk[3]; float ee[3]; unsigned jj[3];
        float esum = 0.f;
        #pragma unroll
        for (int u = 0; u < 3; ++u) {
            int i = lane + u * 64;
            pi[u] = (i < S) ? sv[i] : 0ull;
            rk[u] = 0; ee[u] = 0.f; jj[u] = 0;
        }
        for (int jx = 0; jx < S; ++jx) {
            unsigned long long pj = sv[jx];
            #pragma unroll
            for (int u = 0; u < 3; ++u)
                rk[u] += (pj > pi[u]) ? 1 : 0;
        }
        #pragma unroll
        for (int u = 0; u < 3; ++u) {
            int i = lane + u * 64;
            if (i < S && rk[u] < TK) {
                float val = key2f((unsigned)(pi[u] >> 32));
                ee[u] = __expf(val - Mf);
                jj[u] = 2047u - (unsigned)(pi[u] & 0xFFFFFFFFull);
                esum += ee[u];
            }
        }
        #pragma unroll
        for (int off = 1; off < 64; off <<= 1) esum += __shfl_xor(esum, off);
        #pragma unroll
        for (int u = 0; u < 3; ++u) {
            int i = lane + u * 64;
            if (i < S && rk[u] < TK) { wp[rk[u]] = ee[u] / esum; jp[rk[u]] = jj[u]; }
        }
    } else {
        // exact fallback: iterative argmax (value desc, idx asc)
        unsigned consumed = 0u;
        for (int i = 0; i < TK; ++i) {
            unsigned bk = 0u; unsigned gj = 0xFFFFFFFFu;
            #pragma unroll
            for (int t = 0; t < 32; ++t) {
                if (((consumed >> t) & 1u) == 0u) {
                    unsigned kk = keys[t];
                    unsigned j = (unsigned)((t >> 2) * 256 + lane * 4 + (t & 3));
                    if (kk > bk || (kk == bk && j < gj)) { bk = kk; gj = j; }
                }
            }
            #pragma unroll
            for (int off = 1; off < 64; off <<= 1) {
                unsigned ok = (unsigned)__shfl_xor((int)bk, off);
                unsigned oj = (unsigned)__shfl_xor((int)gj, off);
                if (ok > bk || (ok == bk && oj < gj)) { bk = ok; gj = oj; }
            }
            if (((gj >> 2) & 63u) == (unsigned)lane && gj != 0xFFFFFFFFu) {
                int t = ((int)gj >> 8) * 4 + ((int)gj & 3);
                consumed |= (1u << t);
            }
            if (lane == 0) { wp[i] = key2f(bk); jp[i] = gj; }
        }
        asm volatile("s_waitcnt lgkmcnt(0)" ::: "memory");
        float v = (lane < TK) ? wp[lane] : 0.f;
        float e = (lane < TK) ? __expf(v - Mf) : 0.f;
        float esum = e;
        #pragma unroll
        for (int off = 1; off < 64; off <<= 1) esum += __shfl_xor(esum, off);
        if (lane < TK) wp[lane] = e / esum;
    }
    asm volatile("s_waitcnt lgkmcnt(0)" ::: "memory");

    // ---- out[dd] = sum_i w_i * V[idx_i][dd] ----
    float oacc = 0.f;
    const int dd = lane & 31, half = lane >> 5;
    #pragma unroll
    for (int u2 = 0; u2 < 16; ++u2) {
        int i = half * 16 + u2;
        oacc = fmaf(wp[i], vbase[(size_t)jp[i] * AD + dd], oacc);
    }
    oacc += __shfl_down(oacc, 32);
    if (lane < HD) O[((size_t)b * S_ + q) * AD + h * HD + lane] = oacc;
}

__global__ __launch_bounds__(256)
void concat_kernel()
{
    int i = blockIdx.x * 256 + threadIdx.x;   // over 8192*256
    int row = i >> 8, c = i & 255;
    float v = (c < AD) ? g_ws[OFF_T + row * AD + c]
                       : g_ws[OFF_SB + row * AD + (c - AD)];
    g_ws[OFF_CAT + i] = v;
}

__global__ __launch_bounds__(256)
void fuse_kernel(float* __restrict__ out)
{
    int i = blockIdx.x * 256 + threadIdx.x;   // over 8192*128
    float g = g_ws[OFF_Q + i];
    float f = g_ws[OFF_K + i];
    out[i] = f / (1.0f + expf(-g));           // f * sigmoid(g)
}

extern "C" void kernel_launch(void* const* d_in, const int* in_sizes, int n_in,
                              void* d_out, int out_size, void* d_ws, size_t ws_size,
                              hipStream_t stream)
{
    (void)in_sizes; (void)n_in; (void)d_ws; (void)ws_size; (void)out_size;
    const float* x      = (const float*)d_in[0];
    const float* tp_w   = (const float*)d_in[1];
    const float* tp_b   = (const float*)d_in[2];
    const float* sp_w   = (const float*)d_in[3];
    const float* sp_b   = (const float*)d_in[4];
    const float* gate_w = (const float*)d_in[21];
    const float* gate_b = (const float*)d_in[22];
    const float* fus_w  = (const float*)d_in[23];
    const float* fus_b  = (const float*)d_in[24];

    dim3 gl(128, 2);
    for (int br = 0; br < 2; ++br) {
        const float* pw = br ? sp_w : tp_w;
        const float* pb = br ? sp_b : tp_b;
        int base = 5 + br * 8;
        const float* qw = (const float*)d_in[base + 0];
        const float* qb = (const float*)d_in[base + 1];
        const float* kw = (const float*)d_in[base + 2];
        const float* kb = (const float*)d_in[base + 3];
        const float* vw = (const float*)d_in[base + 4];
        const float* vb = (const float*)d_in[base + 5];
        const float* ow = (const float*)d_in[base + 6];
        const float* ob = (const float*)d_in[base + 7];

        lin_kernel<256><<<gl, 256, 0, stream>>>(x, 0, pw, pb, OFF_PROJ);
        lin3_kernel<128><<<dim3(128, 2, 3), 256, 0, stream>>>(
            OFF_PROJ, qw, qb, OFF_Q, kw, kb, OFF_K, vw, vb, OFF_V);
        score_kernel<<<dim3(32, 32, 16), 256, 0, stream>>>(OFF_Q, OFF_K);
        topk_kernel<<<8192, 256, 0, stream>>>(OFF_V, OFF_ATT);
        lin_kernel<128><<<gl, 256, 0, stream>>>(nullptr, OFF_ATT, ow, ob,
                                                br ? OFF_SB : OFF_T);
    }
    concat_kernel<<<8192, 256, 0, stream>>>();
    lin3_kernel<256><<<dim3(128, 2, 2), 256, 0, stream>>>(
        OFF_CAT, gate_w, gate_b, OFF_Q, fus_w, fus_b, OFF_K,
        (const float*)nullptr, (const float*)nullptr, 0);
    fuse_kernel<<<4096, 256, 0, stream>>>((float*)d_out);
}

// Round 5
// 373.338 us; speedup vs baseline: 13.7990x; 1.2102x over previous
//
#include <hip/hip_runtime.h>
#include <math.h>

#define B_   4
#define S_   2048
#define AD   128
#define NH   4
#define HD   32
#define TK   32
#define SEG  1048576            /* 8192*128 */
#define CAP  192                /* survivor capacity per wave */

#define OFF_PROJ 0
#define OFF_Q    (1 * SEG)
#define OFF_K    (2 * SEG)
#define OFF_V    (3 * SEG)
#define OFF_ATT  (4 * SEG)
#define OFF_T    (5 * SEG)
#define OFF_SB   (6 * SEG)
#define OFF_CAT  (7 * SEG)      /* 2*SEG floats */

__device__ float g_ws[9 * SEG];
__device__ float g_sc[8 * S_ * S_];   /* 128 MB score chunk, reused 4x (L3-resident) */

__device__ __forceinline__ unsigned f2key(float s) {
    unsigned u = __float_as_uint(s);
    return (u & 0x80000000u) ? ~u : (u | 0x80000000u);
}
__device__ __forceinline__ float key2f(unsigned k) {
    unsigned u = (k & 0x80000000u) ? (k & 0x7FFFFFFFu) : ~k;
    return __uint_as_float(u);
}

// Y[M x 128] = X[M x KD] @ W[128 x KD]^T + b.  Transposed-LDS float4 inner loop.
template <int KD>
__global__ __launch_bounds__(256)
void lin_kernel(const float* __restrict__ Xext, int xoff,
                const float* __restrict__ W, const float* __restrict__ Bv,
                int yoff)
{
    const float* X = Xext ? Xext : (const float*)(g_ws + xoff);
    float* Y = g_ws + yoff;
    __shared__ float Xs[32][68];   // [kc][row], pad 68 keeps 16B align + <=2-way banks
    __shared__ float Ws[32][68];
    const int bm = blockIdx.x * 64;
    const int bn = blockIdx.y * 64;
    const int t  = threadIdx.x;
    const int tx = t & 15, ty = t >> 4;
    const int sr = t >> 3, sc4 = t & 7;
    float acc[4][4] = {};
    for (int kk = 0; kk < KD; kk += 32) {
        #pragma unroll
        for (int it = 0; it < 2; ++it) {
            int rr = sr + it * 32;
            float4 xa = *(const float4*)(X + (size_t)(bm + rr) * KD + kk + sc4 * 4);
            float4 wa = *(const float4*)(W + (size_t)(bn + rr) * KD + kk + sc4 * 4);
            Xs[sc4*4+0][rr] = xa.x; Xs[sc4*4+1][rr] = xa.y;
            Xs[sc4*4+2][rr] = xa.z; Xs[sc4*4+3][rr] = xa.w;
            Ws[sc4*4+0][rr] = wa.x; Ws[sc4*4+1][rr] = wa.y;
            Ws[sc4*4+2][rr] = wa.z; Ws[sc4*4+3][rr] = wa.w;
        }
        __syncthreads();
        #pragma unroll
        for (int kc = 0; kc < 32; ++kc) {
            float4 a4 = *(const float4*)&Xs[kc][ty * 4];
            float4 b4 = *(const float4*)&Ws[kc][tx * 4];
            float a[4] = {a4.x, a4.y, a4.z, a4.w};
            float bb[4] = {b4.x, b4.y, b4.z, b4.w};
            #pragma unroll
            for (int i = 0; i < 4; ++i)
                #pragma unroll
                for (int j = 0; j < 4; ++j)
                    acc[i][j] = fmaf(a[i], bb[j], acc[i][j]);
        }
        __syncthreads();
    }
    #pragma unroll
    for (int i = 0; i < 4; ++i) {
        int row = bm + ty * 4 + i;
        int col = bn + tx * 4;
        float4 o;
        o.x = acc[i][0] + Bv[col + 0]; o.y = acc[i][1] + Bv[col + 1];
        o.z = acc[i][2] + Bv[col + 2]; o.w = acc[i][3] + Bv[col + 3];
        *(float4*)(Y + (size_t)row * AD + col) = o;
    }
}

// Up to three GEMMs sharing one X, selected by blockIdx.z.
template <int KD>
__global__ __launch_bounds__(256)
void lin3_kernel(int xoff,
                 const float* __restrict__ W0, const float* __restrict__ B0, int y0,
                 const float* __restrict__ W1, const float* __restrict__ B1, int y1,
                 const float* __restrict__ W2, const float* __restrict__ B2, int y2)
{
    const int z = blockIdx.z;
    const float* X = (const float*)(g_ws + xoff);
    const float* W = (z == 0) ? W0 : (z == 1) ? W1 : W2;
    const float* Bv = (z == 0) ? B0 : (z == 1) ? B1 : B2;
    float* Y = g_ws + ((z == 0) ? y0 : (z == 1) ? y1 : y2);
    __shared__ float Xs[32][68];
    __shared__ float Ws[32][68];
    const int bm = blockIdx.x * 64;
    const int bn = blockIdx.y * 64;
    const int t  = threadIdx.x;
    const int tx = t & 15, ty = t >> 4;
    const int sr = t >> 3, sc4 = t & 7;
    float acc[4][4] = {};
    for (int kk = 0; kk < KD; kk += 32) {
        #pragma unroll
        for (int it = 0; it < 2; ++it) {
            int rr = sr + it * 32;
            float4 xa = *(const float4*)(X + (size_t)(bm + rr) * KD + kk + sc4 * 4);
            float4 wa = *(const float4*)(W + (size_t)(bn + rr) * KD + kk + sc4 * 4);
            Xs[sc4*4+0][rr] = xa.x; Xs[sc4*4+1][rr] = xa.y;
            Xs[sc4*4+2][rr] = xa.z; Xs[sc4*4+3][rr] = xa.w;
            Ws[sc4*4+0][rr] = wa.x; Ws[sc4*4+1][rr] = wa.y;
            Ws[sc4*4+2][rr] = wa.z; Ws[sc4*4+3][rr] = wa.w;
        }
        __syncthreads();
        #pragma unroll
        for (int kc = 0; kc < 32; ++kc) {
            float4 a4 = *(const float4*)&Xs[kc][ty * 4];
            float4 b4 = *(const float4*)&Ws[kc][tx * 4];
            float a[4] = {a4.x, a4.y, a4.z, a4.w};
            float bb[4] = {b4.x, b4.y, b4.z, b4.w};
            #pragma unroll
            for (int i = 0; i < 4; ++i)
                #pragma unroll
                for (int j = 0; j < 4; ++j)
                    acc[i][j] = fmaf(a[i], bb[j], acc[i][j]);
        }
        __syncthreads();
    }
    #pragma unroll
    for (int i = 0; i < 4; ++i) {
        int row = bm + ty * 4 + i;
        int col = bn + tx * 4;
        float4 o;
        o.x = acc[i][0] + Bv[col + 0]; o.y = acc[i][1] + Bv[col + 1];
        o.z = acc[i][2] + Bv[col + 2]; o.w = acc[i][3] + Bv[col + 3];
        *(float4*)(Y + (size_t)row * AD + col) = o;
    }
}

// scores[zh][q][k] = scale * Q[q]·K[k] for head hh = chunk*8 + zh (K-dim = 32).
__global__ __launch_bounds__(256)
void score_kernel(int qoff, int koff, int chunk)
{
    const int zh = blockIdx.z;
    const int hh = chunk * 8 + zh, b = hh >> 2, h = hh & 3;
    const float* Qb = g_ws + qoff + (size_t)b * S_ * AD + h * HD;
    const float* Kb = g_ws + koff + (size_t)b * S_ * AD + h * HD;
    float* Sc = g_sc + (size_t)zh * S_ * S_;
    __shared__ float Qs[32][68];
    __shared__ float Ks[32][68];
    const int t = threadIdx.x, tx = t & 15, ty = t >> 4;
    const int sr = t >> 3, sc4 = t & 7;
    const int q0 = blockIdx.y * 64, k0 = blockIdx.x * 64;
    #pragma unroll
    for (int it = 0; it < 2; ++it) {
        int rr = sr + it * 32;
        float4 qa = *(const float4*)(Qb + (size_t)(q0 + rr) * AD + sc4 * 4);
        float4 ka = *(const float4*)(Kb + (size_t)(k0 + rr) * AD + sc4 * 4);
        Qs[sc4*4+0][rr] = qa.x; Qs[sc4*4+1][rr] = qa.y;
        Qs[sc4*4+2][rr] = qa.z; Qs[sc4*4+3][rr] = qa.w;
        Ks[sc4*4+0][rr] = ka.x; Ks[sc4*4+1][rr] = ka.y;
        Ks[sc4*4+2][rr] = ka.z; Ks[sc4*4+3][rr] = ka.w;
    }
    __syncthreads();
    float acc[4][4] = {};
    #pragma unroll
    for (int kc = 0; kc < 32; ++kc) {
        float4 a4 = *(const float4*)&Qs[kc][ty * 4];
        float4 b4 = *(const float4*)&Ks[kc][tx * 4];
        float a[4] = {a4.x, a4.y, a4.z, a4.w};
        float bb[4] = {b4.x, b4.y, b4.z, b4.w};
        #pragma unroll
        for (int i = 0; i < 4; ++i)
            #pragma unroll
            for (int j = 0; j < 4; ++j)
                acc[i][j] = fmaf(a[i], bb[j], acc[i][j]);
    }
    const float scale = 0.17677669529663688f;  // 1/sqrt(32)
    #pragma unroll
    for (int i = 0; i < 4; ++i) {
        float4 o;
        o.x = acc[i][0] * scale; o.y = acc[i][1] * scale;
        o.z = acc[i][2] * scale; o.w = acc[i][3] * scale;
        *(float4*)(Sc + (size_t)(q0 + ty * 4 + i) * S_ + k0 + tx * 4) = o;
    }
}

// One wave per q-row: coalesced score-row read, exact top-32 via
// threshold-prefilter + rank-by-count (order == lax.top_k), softmax, V-gather.
__global__ __launch_bounds__(256)
void topk_kernel(int voff, int ooff, int chunk)
{
    const float* V = g_ws + voff;
    float* O = g_ws + ooff;

    __shared__ unsigned long long sve[4][CAP];
    __shared__ float    wsel[4][32];
    __shared__ unsigned jsel[4][32];

    const int wid  = threadIdx.x >> 6;
    const int lane = threadIdx.x & 63;
    const int gr   = blockIdx.x * 4 + wid;     // 0..16383
    const int zh   = gr >> 11, q = gr & 2047;
    const int hh   = chunk * 8 + zh;
    const int b    = hh >> 2,  h = hh & 3;

    unsigned long long* sv = sve[wid];
    float*    wp = wsel[wid];
    unsigned* jp = jsel[wid];

    const float* Srow  = g_sc + (size_t)zh * S_ * S_ + (size_t)q * S_;
    const float* vbase = V + (size_t)b * S_ * AD + h * HD;

    // ---- batched loads, then keys; j(t) = (t>>2)*256 + lane*4 + (t&3)
    float4 s4[8];
    #pragma unroll
    for (int i = 0; i < 8; ++i) s4[i] = ((const float4*)Srow)[i * 64 + lane];
    unsigned keys[32];
    unsigned lmax = 0u;
    #pragma unroll
    for (int i = 0; i < 8; ++i) {
        unsigned k0 = f2key(s4[i].x), k1 = f2key(s4[i].y);
        unsigned k2 = f2key(s4[i].z), k3 = f2key(s4[i].w);
        keys[i * 4 + 0] = k0; keys[i * 4 + 1] = k1;
        keys[i * 4 + 2] = k2; keys[i * 4 + 3] = k3;
        unsigned m01 = (k0 > k1) ? k0 : k1;
        unsigned m23 = (k2 > k3) ? k2 : k3;
        unsigned m = (m01 > m23) ? m01 : m23;
        lmax = (m > lmax) ? m : lmax;
    }

    // ---- bitonic sort (ascending) of 64 lane maxima ----
    unsigned bs = lmax;
    #pragma unroll
    for (int k = 2; k <= 64; k <<= 1) {
        #pragma unroll
        for (int j = k >> 1; j > 0; j >>= 1) {
            unsigned o = (unsigned)__shfl_xor((int)bs, j);
            bool up = ((lane & k) == 0);
            bool lower = ((lane & j) == 0);
            bs = (up == lower) ? (bs < o ? bs : o) : (bs > o ? bs : o);
        }
    }
    const unsigned thr  = (unsigned)__shfl((int)bs, 32); // 32nd-largest lane max <= T32
    const unsigned mkey = (unsigned)__shfl((int)bs, 63); // global max
    const float Mf = key2f(mkey);

    // ---- ballot-compact survivors (keys >= thr) ----
    int base = 0;
    const unsigned long long lt = (1ull << lane) - 1ull;
    #pragma unroll
    for (int t = 0; t < 32; ++t) {
        bool pred = keys[t] >= thr;
        unsigned long long m = __ballot(pred);
        int slot = base + __popcll(m & lt);
        if (pred && slot < CAP) {
            unsigned jidx = (unsigned)((t >> 2) * 256 + lane * 4 + (t & 3));
            sv[slot] = ((unsigned long long)keys[t] << 32) | (unsigned)(2047 - jidx);
        }
        base += __popcll(m);
    }
    const int S = base;
    asm volatile("s_waitcnt lgkmcnt(0)" ::: "memory");

    if (S <= 64) {
        unsigned long long pi = (lane < S) ? sv[lane] : 0ull;
        int rank = 0;
        for (int jx = 0; jx < S; ++jx)
            rank += (sv[jx] > pi) ? 1 : 0;
        float e = 0.f; unsigned ji = 0;
        if (lane < S && rank < TK) {
            float val = key2f((unsigned)(pi >> 32));
            e = __expf(val - Mf);
            ji = 2047u - (unsigned)(pi & 0xFFFFFFFFull);
        }
        float esum = e;
        #pragma unroll
        for (int off = 1; off < 64; off <<= 1) esum += __shfl_xor(esum, off);
        if (lane < S && rank < TK) { wp[rank] = e / esum; jp[rank] = ji; }
    } else if (S <= CAP) {
        unsigned long long pi[3]; int rk[3]; float ee[3]; unsigned jj[3];
        float esum = 0.f;
        #pragma unroll
        for (int u = 0; u < 3; ++u) {
            int i = lane + u * 64;
            pi[u] = (i < S) ? sv[i] : 0ull;
            rk[u] = 0; ee[u] = 0.f; jj[u] = 0;
        }
        for (int jx = 0; jx < S; ++jx) {
            unsigned long long pj = sv[jx];
            #pragma unroll
            for (int u = 0; u < 3; ++u)
                rk[u] += (pj > pi[u]) ? 1 : 0;
        }
        #pragma unroll
        for (int u = 0; u < 3; ++u) {
            int i = lane + u * 64;
            if (i < S && rk[u] < TK) {
                float val = key2f((unsigned)(pi[u] >> 32));
                ee[u] = __expf(val - Mf);
                jj[u] = 2047u - (unsigned)(pi[u] & 0xFFFFFFFFull);
                esum += ee[u];
            }
        }
        #pragma unroll
        for (int off = 1; off < 64; off <<= 1) esum += __shfl_xor(esum, off);
        #pragma unroll
        for (int u = 0; u < 3; ++u) {
            int i = lane + u * 64;
            if (i < S && rk[u] < TK) { wp[rk[u]] = ee[u] / esum; jp[rk[u]] = jj[u]; }
        }
    } else {
        // exact fallback: iterative argmax (value desc, idx asc)
        unsigned consumed = 0u;
        for (int i = 0; i < TK; ++i) {
            unsigned bk = 0u; unsigned gj = 0xFFFFFFFFu;
            #pragma unroll
            for (int t = 0; t < 32; ++t) {
                if (((consumed >> t) & 1u) == 0u) {
                    unsigned kk = keys[t];
                    unsigned j = (unsigned)((t >> 2) * 256 + lane * 4 + (t & 3));
                    if (kk > bk || (kk == bk && j < gj)) { bk = kk; gj = j; }
                }
            }
            #pragma unroll
            for (int off = 1; off < 64; off <<= 1) {
                unsigned ok = (unsigned)__shfl_xor((int)bk, off);
                unsigned oj = (unsigned)__shfl_xor((int)gj, off);
                if (ok > bk || (ok == bk && oj < gj)) { bk = ok; gj = oj; }
            }
            if (((gj >> 2) & 63u) == (unsigned)lane && gj != 0xFFFFFFFFu) {
                int t = ((int)gj >> 8) * 4 + ((int)gj & 3);
                consumed |= (1u << t);
            }
            if (lane == 0) { wp[i] = key2f(bk); jp[i] = gj; }
        }
        asm volatile("s_waitcnt lgkmcnt(0)" ::: "memory");
        float v = (lane < TK) ? wp[lane] : 0.f;
        float e = (lane < TK) ? __expf(v - Mf) : 0.f;
        float esum = e;
        #pragma unroll
        for (int off = 1; off < 64; off <<= 1) esum += __shfl_xor(esum, off);
        if (lane < TK) wp[lane] = e / esum;
    }
    asm volatile("s_waitcnt lgkmcnt(0)" ::: "memory");

    // ---- out[dd] = sum_i w_i * V[idx_i][dd] ----
    float oacc = 0.f;
    const int dd = lane & 31, half = lane >> 5;
    #pragma unroll
    for (int u2 = 0; u2 < 16; ++u2) {
        int i = half * 16 + u2;
        oacc = fmaf(wp[i], vbase[(size_t)jp[i] * AD + dd], oacc);
    }
    oacc += __shfl_down(oacc, 32);
    if (lane < HD) O[((size_t)b * S_ + q) * AD + h * HD + lane] = oacc;
}

__global__ __launch_bounds__(256)
void concat_kernel()
{
    int i = blockIdx.x * 256 + threadIdx.x;   // over 8192*256
    int row = i >> 8, c = i & 255;
    float v = (c < AD) ? g_ws[OFF_T + row * AD + c]
                       : g_ws[OFF_SB + row * AD + (c - AD)];
    g_ws[OFF_CAT + i] = v;
}

__global__ __launch_bounds__(256)
void fuse_kernel(float* __restrict__ out)
{
    int i = blockIdx.x * 256 + threadIdx.x;   // over 8192*128
    float g = g_ws[OFF_Q + i];
    float f = g_ws[OFF_K + i];
    out[i] = f / (1.0f + expf(-g));           // f * sigmoid(g)
}

extern "C" void kernel_launch(void* const* d_in, const int* in_sizes, int n_in,
                              void* d_out, int out_size, void* d_ws, size_t ws_size,
                              hipStream_t stream)
{
    (void)in_sizes; (void)n_in; (void)d_ws; (void)ws_size; (void)out_size;
    const float* x      = (const float*)d_in[0];
    const float* tp_w   = (const float*)d_in[1];
    const float* tp_b   = (const float*)d_in[2];
    const float* sp_w   = (const float*)d_in[3];
    const float* sp_b   = (const float*)d_in[4];
    const float* gate_w = (const float*)d_in[21];
    const float* gate_b = (const float*)d_in[22];
    const float* fus_w  = (const float*)d_in[23];
    const float* fus_b  = (const float*)d_in[24];

    dim3 gl(128, 2);
    for (int br = 0; br < 2; ++br) {
        const float* pw = br ? sp_w : tp_w;
        const float* pb = br ? sp_b : tp_b;
        int base = 5 + br * 8;
        const float* qw = (const float*)d_in[base + 0];
        const float* qb = (const float*)d_in[base + 1];
        const float* kw = (const float*)d_in[base + 2];
        const float* kb = (const float*)d_in[base + 3];
        const float* vw = (const float*)d_in[base + 4];
        const float* vb = (const float*)d_in[base + 5];
        const float* ow = (const float*)d_in[base + 6];
        const float* ob = (const float*)d_in[base + 7];

        lin_kernel<256><<<gl, 256, 0, stream>>>(x, 0, pw, pb, OFF_PROJ);
        lin3_kernel<128><<<dim3(128, 2, 3), 256, 0, stream>>>(
            OFF_PROJ, qw, qb, OFF_Q, kw, kb, OFF_K, vw, vb, OFF_V);
        for (int chunk = 0; chunk < 2; ++chunk) {
            score_kernel<<<dim3(32, 32, 8), 256, 0, stream>>>(OFF_Q, OFF_K, chunk);
            topk_kernel<<<4096, 256, 0, stream>>>(OFF_V, OFF_ATT, chunk);
        }
        lin_kernel<128><<<gl, 256, 0, stream>>>(nullptr, OFF_ATT, ow, ob,
                                                br ? OFF_SB : OFF_T);
    }
    concat_kernel<<<8192, 256, 0, stream>>>();
    lin3_kernel<256><<<dim3(128, 2, 2), 256, 0, stream>>>(
        OFF_CAT, gate_w, gate_b, OFF_Q, fus_w, fus_b, OFF_K,
        (const float*)nullptr, (const float*)nullptr, 0);
    fuse_kernel<<<4096, 256, 0, stream>>>((float*)d_out);
}